// Round 4
// baseline (245.828 us; speedup 1.0000x reference)
//
#include <hip/hip_runtime.h>

#define D_IN   96
#define D_OUT  256
#define BN_EPS 1e-3f
#define TROWS  32            // rows per block tile in the fused kernel
#define CAP    64            // fixed edge capacity per row (deg~Pois(16))
#define N_PAD  50048
#define RS1    104           // Abuf row stride (96+8 bf16)
#define RS2    264           // Hbuf row stride (256+8 bf16)

typedef __attribute__((ext_vector_type(8))) short  short8;   // 8 bf16 = 4 VGPRs
typedef __attribute__((ext_vector_type(4))) float  floatx4;  // MFMA C/D
typedef __attribute__((ext_vector_type(4))) int    intx4;    // nontemporal-ok int4

__device__ __forceinline__ unsigned short f2bf(float f) {   // RNE fp32->bf16
    unsigned int u = __float_as_uint(f);
    unsigned int r = u + 0x7FFFu + ((u >> 16) & 1u);
    return (unsigned short)(r >> 16);
}
__device__ __forceinline__ float bfbits(unsigned short u) { // bf16 bits -> f32
    return __uint_as_float(((unsigned int)u) << 16);
}

// ---------------------------------------------------------------------------
// Fused prep: block-role partitioned.
//  [0, nscat):        edge bucket scatter — 1 edge/thread. PLAIN store
//                     (r3's nontemporal store write-amplified 3.2MB of random
//                     4B stores into ~51MB HBM write-through: prep 50->60us).
//  [nscat, +nxc):     x fp32 -> bf16, 8 elems/thread
//  [.., +nwc):        W0/W1 fp32 -> bf16 B-fragment swizzle [kb][n][32]
// ---------------------------------------------------------------------------
__global__ __launch_bounds__(256) void prep(
    const int* __restrict__ src, const int* __restrict__ dst,
    const float* __restrict__ vals, const float* __restrict__ x,
    const float* __restrict__ W0, const float* __restrict__ W1,
    int* __restrict__ cursor, int* __restrict__ bucket,
    unsigned short* __restrict__ xbf,
    unsigned short* __restrict__ W0p, unsigned short* __restrict__ W1p,
    int E, int n, int nscat, int nxc)
{
    const int b = blockIdx.x, tid = threadIdx.x;
    if (b < nscat) {
        int t = b * 256 + tid;
        if (t < E) {
            int d = dst[t];
            unsigned int u = __float_as_uint(vals[t]);
            unsigned int vhi = (u + 0x7FFFu + ((u >> 16) & 1u)) & 0xFFFF0000u;
            int pos = atomicAdd(&cursor[d], 1);
            if (pos < CAP)                       // OOB-safe (stat. never hit)
                bucket[((size_t)d << 6) + pos] = (int)(vhi | (unsigned int)src[t]);
        }
    } else if (b < nscat + nxc) {
        size_t t   = (size_t)(b - nscat) * 256 + tid;   // 8 floats per thread
        size_t off = t * 8;
        if (off < (size_t)n * D_IN) {
            float4 v0 = *(const float4*)(x + off);
            float4 v1 = *(const float4*)(x + off + 4);
            ushort4 o0, o1;
            o0.x = f2bf(v0.x); o0.y = f2bf(v0.y); o0.z = f2bf(v0.z); o0.w = f2bf(v0.w);
            o1.x = f2bf(v1.x); o1.y = f2bf(v1.y); o1.z = f2bf(v1.z); o1.w = f2bf(v1.w);
            *(ushort4*)(xbf + off)     = o0;
            *(ushort4*)(xbf + off + 4) = o1;
        }
    } else {
        int o = (b - nscat - nxc) * 256 + tid;
        const int n0 = 3 * 256 * 32;             // W0p elems (K=96)
        const int n1 = 8 * 256 * 32;             // W1p elems (K=256)
        if (o < n0) {
            int kk = o & 31, nn = (o >> 5) & 255, kb = o >> 13;
            W0p[o] = f2bf(W0[(size_t)(kb * 32 + kk) * 256 + nn]);
        } else if (o < n0 + n1) {
            int o2 = o - n0;
            int kk = o2 & 31, nn = (o2 >> 5) & 255, kb = o2 >> 13;
            W1p[o2] = f2bf(W1[(size_t)(kb * 32 + kk) * 256 + nn]);
        }
    }
}

// ---------------------------------------------------------------------------
// Fused GIN kernel.  VAR: 0 = real (full pipeline, writes out)
//                         1 = ABLATION pull-only  (acc checksum -> scratch)
//                         2 = ABLATION gemm-only  (acc2 checksum -> scratch)
// Ablation dispatches run AFTER the real one, write only to scratch
// (disjoint from bucket/xbf which VAR=1 still reads). Checksum stores keep
// all gathers / MFMA live (value-dependent -> no DCE, rule #17).
// ---------------------------------------------------------------------------
template<bool BF16X, int VAR>
__global__ __launch_bounds__(256) void gin_fused(
    const float* __restrict__ x, const unsigned short* __restrict__ xbf,
    const int* __restrict__ deg, const int* __restrict__ bucket,
    const float* __restrict__ epsp,
    const unsigned short* __restrict__ W0p, const unsigned short* __restrict__ W1p,
    const float* __restrict__ gamma, const float* __restrict__ beta,
    const float* __restrict__ bn_mean, const float* __restrict__ bn_var,
    float* __restrict__ out, float* __restrict__ scratch, int n)
{
    __shared__ __align__(16) unsigned short SMEM[TROWS * RS2]; // 16896 B
    __shared__ float bn_scale[D_OUT];
    __shared__ float bn_shift[D_OUT];
    unsigned short (*Abuf)[RS1] = (unsigned short (*)[RS1])SMEM; // alias (phase 1)
    unsigned short (*Hbuf)[RS2] = (unsigned short (*)[RS2])SMEM; // alias (phase 2)

    const int tid = threadIdx.x;
    const int rowbase = blockIdx.x * TROWS;
    const float epsv = *epsp;

    // BN constants -> LDS (consumed after the barrier)
    {
        float sc = gamma[tid] * rsqrtf(bn_var[tid] + BN_EPS);
        bn_scale[tid] = sc;
        bn_shift[tid] = fmaf(-bn_mean[tid], sc, beta[tid]);
    }

    // ---- Pull phase (skipped for VAR==2) ----------------------------------
    if (VAR != 2) {
        const int j   = tid & 7;          // 12-col group
        const int rl  = tid >> 3;         // 0..31
        const int row = rowbase + rl;
        float acc[12];
#pragma unroll
        for (int q = 0; q < 12; ++q) acc[q] = 0.f;

        if (row < n) {
            const int dg = min(deg[row], CAP);
            const int* ep = bucket + ((size_t)row << 6);

#define EDGE_FMA(vv, A, B, C)                                              \
            { acc[0] = fmaf(vv, A.x, acc[0]); acc[1] = fmaf(vv, A.y, acc[1]);  \
              acc[2] = fmaf(vv, A.z, acc[2]); acc[3] = fmaf(vv, A.w, acc[3]);  \
              acc[4] = fmaf(vv, B.x, acc[4]); acc[5] = fmaf(vv, B.y, acc[5]);  \
              acc[6] = fmaf(vv, B.z, acc[6]); acc[7] = fmaf(vv, B.w, acc[7]);  \
              acc[8] = fmaf(vv, C.x, acc[8]); acc[9] = fmaf(vv, C.y, acc[9]);  \
              acc[10] = fmaf(vv, C.z, acc[10]); acc[11] = fmaf(vv, C.w, acc[11]); }

            if (BF16X) {
                const int nm1 = n - 1;
                // self-row (eps residual): independent load, issued up-front
                const unsigned short* rr = xbf + (size_t)row * D_IN + j * 12;
                ushort4 sa = *(const ushort4*)(rr);
                ushort4 sb = *(const ushort4*)(rr + 4);
                ushort4 sc = *(const ushort4*)(rr + 8);

                // preload 32 packed (val<<16|src) words: 8 independent intx4
                int w[32];
                {
                    const intx4* ep4 = (const intx4*)ep;
#pragma unroll
                    for (int q = 0; q < 8; ++q) {
                        intx4 t = __builtin_nontemporal_load(ep4 + q);
                        w[4 * q + 0] = t.x; w[4 * q + 1] = t.y;
                        w[4 * q + 2] = t.z; w[4 * q + 3] = t.w;
                    }
                }

#pragma unroll
                for (int eb = 0; eb < 8; ++eb) {
                    if (eb * 4 >= dg) break;     // divergent quad skip (ok)
#pragma unroll
                    for (int u = 0; u < 4; ++u) {
                        const int e = eb * 4 + u;        // compile-time index
                        int p = w[e];
                        float v = (e < dg)
                            ? __uint_as_float((unsigned int)p & 0xFFFF0000u)
                            : 0.f;                        // predicate via value
                        int idx = min(p & 0xFFFF, nm1);   // poison-safe clamp
                        const unsigned short* r0 =
                            xbf + (size_t)idx * D_IN + j * 12;
                        ushort4 a0 = *(const ushort4*)(r0);
                        ushort4 b0 = *(const ushort4*)(r0 + 4);
                        ushort4 c0 = *(const ushort4*)(r0 + 8);
                        float4 A, B, C;
                        A.x = bfbits(a0.x); A.y = bfbits(a0.y); A.z = bfbits(a0.z); A.w = bfbits(a0.w);
                        B.x = bfbits(b0.x); B.y = bfbits(b0.y); B.z = bfbits(b0.z); B.w = bfbits(b0.w);
                        C.x = bfbits(c0.x); C.y = bfbits(c0.y); C.z = bfbits(c0.z); C.w = bfbits(c0.w);
                        EDGE_FMA(v, A, B, C)
                    }
                }
                // residual: dg > 32 (rare)
                for (int e = 32; e < dg; ++e) {
                    int p0 = __builtin_nontemporal_load(ep + e);
                    float v0 = __uint_as_float((unsigned int)p0 & 0xFFFF0000u);
                    const unsigned short* r0 = xbf + (size_t)(p0 & 0xFFFF) * D_IN + j * 12;
                    ushort4 a0 = *(const ushort4*)(r0), b0 = *(const ushort4*)(r0 + 4), c0 = *(const ushort4*)(r0 + 8);
                    float4 A, B, C;
                    A.x = bfbits(a0.x); A.y = bfbits(a0.y); A.z = bfbits(a0.z); A.w = bfbits(a0.w);
                    B.x = bfbits(b0.x); B.y = bfbits(b0.y); B.z = bfbits(b0.z); B.w = bfbits(b0.w);
                    C.x = bfbits(c0.x); C.y = bfbits(c0.y); C.z = bfbits(c0.z); C.w = bfbits(c0.w);
                    EDGE_FMA(v0, A, B, C)
                }
                // eps * self
                {
                    float4 A, B, C;
                    A.x = bfbits(sa.x); A.y = bfbits(sa.y); A.z = bfbits(sa.z); A.w = bfbits(sa.w);
                    B.x = bfbits(sb.x); B.y = bfbits(sb.y); B.z = bfbits(sb.z); B.w = bfbits(sb.w);
                    C.x = bfbits(sc.x); C.y = bfbits(sc.y); C.z = bfbits(sc.z); C.w = bfbits(sc.w);
                    EDGE_FMA(epsv, A, B, C)
                }
            } else {
                int e = 0;
                for (; e + 2 <= dg; e += 2) {
                    int p0 = __builtin_nontemporal_load(ep + e);
                    int p1 = __builtin_nontemporal_load(ep + e + 1);
                    float v0 = __uint_as_float((unsigned int)p0 & 0xFFFF0000u);
                    float v1 = __uint_as_float((unsigned int)p1 & 0xFFFF0000u);
                    const float* r0 = x + (size_t)(p0 & 0xFFFF) * D_IN + j * 12;
                    const float* r1 = x + (size_t)(p1 & 0xFFFF) * D_IN + j * 12;
                    float4 A0 = *(const float4*)(r0), B0 = *(const float4*)(r0 + 4), C0 = *(const float4*)(r0 + 8);
                    float4 A1 = *(const float4*)(r1), B1 = *(const float4*)(r1 + 4), C1 = *(const float4*)(r1 + 8);
                    EDGE_FMA(v0, A0, B0, C0)
                    EDGE_FMA(v1, A1, B1, C1)
                }
                for (; e < dg; ++e) {
                    int p0 = __builtin_nontemporal_load(ep + e);
                    float v0 = __uint_as_float((unsigned int)p0 & 0xFFFF0000u);
                    const float* r0 = x + (size_t)(p0 & 0xFFFF) * D_IN + j * 12;
                    float4 A0 = *(const float4*)(r0), B0 = *(const float4*)(r0 + 4), C0 = *(const float4*)(r0 + 8);
                    EDGE_FMA(v0, A0, B0, C0)
                }
                const float* rr = x + (size_t)row * D_IN + j * 12;
                float4 A0 = *(const float4*)(rr), B0 = *(const float4*)(rr + 4), C0 = *(const float4*)(rr + 8);
                EDGE_FMA(epsv, A0, B0, C0)
            }
#undef EDGE_FMA
        }

        if (VAR == 1) {   // ABLATION: keep pull live, skip GEMM entirely
            float s = 0.f;
#pragma unroll
            for (int q = 0; q < 12; ++q) s += acc[q];
            scratch[(size_t)blockIdx.x * 256 + tid] = s;
            return;       // uniform exit, no barrier executed by any thread
        }

        // write 12 bf16 as 6 dwords (4B-aligned: byte off = 24j + 4q)
#pragma unroll
        for (int q = 0; q < 6; ++q) {
            unsigned int lo = f2bf(acc[2 * q]);
            unsigned int hi = f2bf(acc[2 * q + 1]);
            *(unsigned int*)&Abuf[rl][j * 12 + 2 * q] = lo | (hi << 16);
        }
    }
    __syncthreads();

    const int lane = tid & 63;
    const int wid  = tid >> 6;        // wave: cols [wid*64, wid*64+64)
    const int quad = lane >> 4;
    const int nl   = lane & 15;

    // ---- GEMM1 (M=32, N=64/wave, K=96) ------------------------------------
    floatx4 acc1[2][4];
#pragma unroll
    for (int mt = 0; mt < 2; ++mt)
#pragma unroll
        for (int nt = 0; nt < 4; ++nt)
            acc1[mt][nt] = (floatx4){0.f, 0.f, 0.f, 0.f};

#pragma unroll
    for (int kb = 0; kb < 3; ++kb) {
        short8 af0 = *(const short8*)&Abuf[nl     ][kb * 32 + quad * 8];
        short8 af1 = *(const short8*)&Abuf[16 + nl][kb * 32 + quad * 8];
#pragma unroll
        for (int nt = 0; nt < 4; ++nt) {
            const unsigned short* bp =
                W0p + ((size_t)(kb * 256 + wid * 64 + nt * 16 + nl)) * 32 + quad * 8;
            short8 bf = *(const short8*)bp;
            acc1[0][nt] = __builtin_amdgcn_mfma_f32_16x16x32_bf16(af0, bf, acc1[0][nt], 0, 0, 0);
            acc1[1][nt] = __builtin_amdgcn_mfma_f32_16x16x32_bf16(af1, bf, acc1[1][nt], 0, 0, 0);
        }
    }
    __syncthreads();   // Abuf fully consumed by ALL waves before Hbuf overwrite

    // ---- BN + ReLU -> Hbuf (bf16, A-layout for GEMM2) ---------------------
#pragma unroll
    for (int mt = 0; mt < 2; ++mt)
#pragma unroll
        for (int nt = 0; nt < 4; ++nt) {
            int ncol = wid * 64 + nt * 16 + nl;
            float sc = bn_scale[ncol], sh = bn_shift[ncol];
#pragma unroll
            for (int r = 0; r < 4; ++r) {
                float h = fmaxf(0.f, fmaf(acc1[mt][nt][r], sc, sh));
                Hbuf[mt * 16 + quad * 4 + r][ncol] = f2bf(h);
            }
        }
    __syncthreads();

    // ---- GEMM2 (M=32, N=64/wave, K=256) -----------------------------------
    floatx4 acc2[2][4];
#pragma unroll
    for (int mt = 0; mt < 2; ++mt)
#pragma unroll
        for (int nt = 0; nt < 4; ++nt)
            acc2[mt][nt] = (floatx4){0.f, 0.f, 0.f, 0.f};

#pragma unroll
    for (int kb = 0; kb < 8; ++kb) {
        short8 af0 = *(const short8*)&Hbuf[nl     ][kb * 32 + quad * 8];
        short8 af1 = *(const short8*)&Hbuf[16 + nl][kb * 32 + quad * 8];
#pragma unroll
        for (int nt = 0; nt < 4; ++nt) {
            const unsigned short* bp =
                W1p + ((size_t)(kb * 256 + wid * 64 + nt * 16 + nl)) * 32 + quad * 8;
            short8 bf = *(const short8*)bp;
            acc2[0][nt] = __builtin_amdgcn_mfma_f32_16x16x32_bf16(af0, bf, acc2[0][nt], 0, 0, 0);
            acc2[1][nt] = __builtin_amdgcn_mfma_f32_16x16x32_bf16(af1, bf, acc2[1][nt], 0, 0, 0);
        }
    }

    if (VAR == 2) {   // ABLATION: keep B-loads+MFMA+BN live, skip real store
        float s = 0.f;
#pragma unroll
        for (int mt = 0; mt < 2; ++mt)
#pragma unroll
            for (int nt = 0; nt < 4; ++nt)
#pragma unroll
                for (int r = 0; r < 4; ++r) s += acc2[mt][nt][r];
        scratch[(size_t)blockIdx.x * 256 + tid] = s;
        return;
    }

    // ---- Store ------------------------------------------------------------
#pragma unroll
    for (int mt = 0; mt < 2; ++mt)
#pragma unroll
        for (int nt = 0; nt < 4; ++nt) {
            int ncol = wid * 64 + nt * 16 + nl;
#pragma unroll
            for (int r = 0; r < 4; ++r) {
                int m = rowbase + mt * 16 + quad * 4 + r;
                if (m < n)
                    __builtin_nontemporal_store(acc2[mt][nt][r],
                                                out + (size_t)m * D_OUT + ncol);
            }
        }
}

extern "C" void kernel_launch(void* const* d_in, const int* in_sizes, int n_in,
                              void* d_out, int out_size, void* d_ws, size_t ws_size,
                              hipStream_t stream) {
    const float* x       = (const float*)d_in[0];
    const int*   src     = (const int*)  d_in[1];
    const int*   dst     = (const int*)  d_in[2];
    const float* vals    = (const float*)d_in[3];
    const float* epsp    = (const float*)d_in[4];
    const float* W0      = (const float*)d_in[5];
    const float* W1      = (const float*)d_in[6];
    const float* gamma   = (const float*)d_in[7];
    const float* beta    = (const float*)d_in[8];
    const float* bn_mean = (const float*)d_in[9];
    const float* bn_var  = (const float*)d_in[10];
    float* out = (float*)d_out;

    const int n = in_sizes[0] / D_IN;
    const int E = in_sizes[1];

    // workspace layout (re-poisoned every call -> rebuild everything)
    int* cursor = (int*)d_ws;                               // N_PAD ints
    int* bucket = cursor + N_PAD;                           // n*CAP ints (12.8 MB)
    unsigned short* W0p = (unsigned short*)(bucket + (size_t)n * CAP);
    unsigned short* W1p = W0p + 3 * 256 * 32;
    unsigned short* xbf = W1p + 8 * 256 * 32;               // n*96 bf16 (9.6 MB), optional
    float* scratch = (float*)(xbf + (size_t)n * D_IN);      // ablation scratch

    const int gblocks = (n + TROWS - 1) / TROWS;
    const size_t base_need = (size_t)(N_PAD + (size_t)n * CAP) * 4
                           + (size_t)(3 + 8) * 256 * 32 * 2;
    const bool use_bf16x = ws_size >= base_need + (size_t)n * D_IN * 2;
    const bool do_abl    = use_bf16x &&
        ws_size >= base_need + (size_t)n * D_IN * 2 + (size_t)gblocks * 256 * 4;

    (void)hipMemsetAsync(cursor, 0, (size_t)n * sizeof(int), stream);

    const int nscat = (E + 255) / 256;                      // 1 edge/thread
    const int nxc   = use_bf16x ? ((n * D_IN / 8) + 255) / 256 : 0;  // 8 elems/thread
    const int nwc   = ((3 + 8) * 256 * 32 + 255) / 256;
    prep<<<nscat + nxc + nwc, 256, 0, stream>>>(
        src, dst, vals, x, W0, W1, cursor, bucket, xbf, W0p, W1p, E, n, nscat, nxc);

    if (use_bf16x) {
        gin_fused<true, 0><<<gblocks, 256, 0, stream>>>(
            x, xbf, cursor, bucket, epsp, W0p, W1p,
            gamma, beta, bn_mean, bn_var, out, scratch, n);
        if (do_abl) {   // diagnostics: per-dispatch dur_us read from rocprof
            gin_fused<true, 1><<<gblocks, 256, 0, stream>>>(
                x, xbf, cursor, bucket, epsp, W0p, W1p,
                gamma, beta, bn_mean, bn_var, out, scratch, n);
            gin_fused<true, 2><<<gblocks, 256, 0, stream>>>(
                x, xbf, cursor, bucket, epsp, W0p, W1p,
                gamma, beta, bn_mean, bn_var, out, scratch, n);
        }
    } else {
        gin_fused<false, 0><<<gblocks, 256, 0, stream>>>(
            x, xbf, cursor, bucket, epsp, W0p, W1p,
            gamma, beta, bn_mean, bn_var, out, scratch, n);
    }
}

// Round 5
// 192.472 us; speedup vs baseline: 1.2772x; 1.2772x over previous
//
#include <hip/hip_runtime.h>

#define D_IN   96
#define D_OUT  256
#define BN_EPS 1e-3f
#define TROWS  32            // rows per block tile in the fused kernel
#define CAP    64            // fixed edge capacity per row (deg~Pois(16))
#define N_PAD  50048
#define RS1    104           // Abuf row stride (96+8 bf16) = 208 B (8B-aligned)
#define RS2    264           // Hbuf row stride (256+8 bf16)

typedef __attribute__((ext_vector_type(8))) short  short8;   // 8 bf16 = 4 VGPRs
typedef __attribute__((ext_vector_type(4))) float  floatx4;  // MFMA C/D
typedef __attribute__((ext_vector_type(4))) int    intx4;    // nontemporal-ok int4
typedef __attribute__((ext_vector_type(2))) unsigned int uintx2;

__device__ __forceinline__ unsigned short f2bf(float f) {   // RNE fp32->bf16
    unsigned int u = __float_as_uint(f);
    unsigned int r = u + 0x7FFFu + ((u >> 16) & 1u);
    return (unsigned short)(r >> 16);
}
__device__ __forceinline__ float bfbits(unsigned short u) { // bf16 bits -> f32
    return __uint_as_float(((unsigned int)u) << 16);
}

// ---------------------------------------------------------------------------
// Fused prep: block-role partitioned.
//  [0, nscat):        edge bucket scatter — 1 edge/thread, PLAIN store
//                     (NT store write-amplified: 50->60us r3; reverted r4 ok).
//  [nscat, +nxc):     x fp32 -> bf16, 8 elems/thread
//  [.., +nwc):        W0/W1 fp32 -> bf16 B-fragment swizzle [kb][n][32]
// ---------------------------------------------------------------------------
__global__ __launch_bounds__(256) void prep(
    const int* __restrict__ src, const int* __restrict__ dst,
    const float* __restrict__ vals, const float* __restrict__ x,
    const float* __restrict__ W0, const float* __restrict__ W1,
    int* __restrict__ cursor, int* __restrict__ bucket,
    unsigned short* __restrict__ xbf,
    unsigned short* __restrict__ W0p, unsigned short* __restrict__ W1p,
    int E, int n, int nscat, int nxc)
{
    const int b = blockIdx.x, tid = threadIdx.x;
    if (b < nscat) {
        int t = b * 256 + tid;
        if (t < E) {
            int s = src[t];                      // independent loads first
            float vv = vals[t];
            int d = dst[t];
            unsigned int u = __float_as_uint(vv);
            unsigned int vhi = (u + 0x7FFFu + ((u >> 16) & 1u)) & 0xFFFF0000u;
            int pos = atomicAdd(&cursor[d], 1);
            if (pos < CAP)                       // OOB-safe (stat. never hit)
                bucket[((size_t)d << 6) + pos] = (int)(vhi | (unsigned int)s);
        }
    } else if (b < nscat + nxc) {
        size_t t   = (size_t)(b - nscat) * 256 + tid;   // 8 floats per thread
        size_t off = t * 8;
        if (off < (size_t)n * D_IN) {
            float4 v0 = *(const float4*)(x + off);
            float4 v1 = *(const float4*)(x + off + 4);
            ushort4 o0, o1;
            o0.x = f2bf(v0.x); o0.y = f2bf(v0.y); o0.z = f2bf(v0.z); o0.w = f2bf(v0.w);
            o1.x = f2bf(v1.x); o1.y = f2bf(v1.y); o1.z = f2bf(v1.z); o1.w = f2bf(v1.w);
            *(ushort4*)(xbf + off)     = o0;
            *(ushort4*)(xbf + off + 4) = o1;
        }
    } else {
        int o = (b - nscat - nxc) * 256 + tid;
        const int n0 = 3 * 256 * 32;             // W0p elems (K=96)
        const int n1 = 8 * 256 * 32;             // W1p elems (K=256)
        if (o < n0) {
            int kk = o & 31, nn = (o >> 5) & 255, kb = o >> 13;
            W0p[o] = f2bf(W0[(size_t)(kb * 32 + kk) * 256 + nn]);
        } else if (o < n0 + n1) {
            int o2 = o - n0;
            int kk = o2 & 31, nn = (o2 >> 5) & 255, kb = o2 >> 13;
            W1p[o2] = f2bf(W1[(size_t)(kb * 32 + kk) * 256 + nn]);
        }
    }
}

// ---------------------------------------------------------------------------
// Fused: pull-mode SpMM + eps residual -> MFMA GEMM1 -> BN -> ReLU ->
//        MFMA GEMM2 -> store.  Block = 256 threads (4 waves), 32-row tile.
//
// Pull v3 (segment-coalesced gather): ablation (r4) showed pull dominates
// (~35us) and is request-THROUGHPUT-bound (ILP fix was a no-op). Old mapping
// (lane j = 12 contiguous cols, byte j*24) made every gather instruction
// touch all 3 64B segments of the 192B row -> 24 segs/instr (8 rows/wave).
// New mapping: lane j owns cols {4j..4j+3, 32+4j.., 64+4j..}; each load reads
// bytes c*64 + j*8 -> the 8 lanes of a row-group cover EXACTLY one 64B
// segment -> 8 segs/instr, 3x fewer L1/L2 transactions. Abuf stays [row][col]
// row-major so both GEMMs are unchanged; only LDS-write addressing differs.
// acc[k]: k=0..3 -> col 4j+k; 4..7 -> col 32+4j+(k-4); 8..11 -> 64+4j+(k-8).
// ---------------------------------------------------------------------------
template<bool BF16X>
__global__ __launch_bounds__(256) void gin_fused(
    const float* __restrict__ x, const unsigned short* __restrict__ xbf,
    const int* __restrict__ deg, const int* __restrict__ bucket,
    const float* __restrict__ epsp,
    const unsigned short* __restrict__ W0p, const unsigned short* __restrict__ W1p,
    const float* __restrict__ gamma, const float* __restrict__ beta,
    const float* __restrict__ bn_mean, const float* __restrict__ bn_var,
    float* __restrict__ out, int n)
{
    __shared__ __align__(16) unsigned short SMEM[TROWS * RS2]; // 16896 B
    __shared__ float bn_scale[D_OUT];
    __shared__ float bn_shift[D_OUT];
    unsigned short (*Abuf)[RS1] = (unsigned short (*)[RS1])SMEM; // alias (phase 1)
    unsigned short (*Hbuf)[RS2] = (unsigned short (*)[RS2])SMEM; // alias (phase 2)

    const int tid = threadIdx.x;
    const int rowbase = blockIdx.x * TROWS;
    const float epsv = *epsp;

    // BN constants -> LDS (consumed after the barrier)
    {
        float sc = gamma[tid] * rsqrtf(bn_var[tid] + BN_EPS);
        bn_scale[tid] = sc;
        bn_shift[tid] = fmaf(-bn_mean[tid], sc, beta[tid]);
    }

    // ---- Pull phase -------------------------------------------------------
    {
        const int j   = tid & 7;          // owns cols {4j+k + 32c}
        const int rl  = tid >> 3;         // 0..31
        const int row = rowbase + rl;
        float acc[12];
#pragma unroll
        for (int q = 0; q < 12; ++q) acc[q] = 0.f;

#define EDGE_FMA(vv, A, B, C)                                              \
            { acc[0] = fmaf(vv, A.x, acc[0]); acc[1] = fmaf(vv, A.y, acc[1]);  \
              acc[2] = fmaf(vv, A.z, acc[2]); acc[3] = fmaf(vv, A.w, acc[3]);  \
              acc[4] = fmaf(vv, B.x, acc[4]); acc[5] = fmaf(vv, B.y, acc[5]);  \
              acc[6] = fmaf(vv, B.z, acc[6]); acc[7] = fmaf(vv, B.w, acc[7]);  \
              acc[8] = fmaf(vv, C.x, acc[8]); acc[9] = fmaf(vv, C.y, acc[9]);  \
              acc[10] = fmaf(vv, C.z, acc[10]); acc[11] = fmaf(vv, C.w, acc[11]); }

        if (row < n) {
            const int dg = min(deg[row], CAP);
            const int* ep = bucket + ((size_t)row << 6);
            const int jo = j << 2;                 // ushort offset within chunk

            if (BF16X) {
                const int nm1 = n - 1;
                // self-row (eps residual): independent load, issued up-front
                const unsigned short* rr = xbf + (size_t)row * D_IN;
                ushort4 sa = *(const ushort4*)(rr + jo);
                ushort4 sb = *(const ushort4*)(rr + 32 + jo);
                ushort4 sc = *(const ushort4*)(rr + 64 + jo);

                // preload 32 packed (val<<16|src) words: 8 independent intx4
                int w[32];
                {
                    const intx4* ep4 = (const intx4*)ep;
#pragma unroll
                    for (int q = 0; q < 8; ++q) {
                        intx4 t = __builtin_nontemporal_load(ep4 + q);
                        w[4 * q + 0] = t.x; w[4 * q + 1] = t.y;
                        w[4 * q + 2] = t.z; w[4 * q + 3] = t.w;
                    }
                }

#pragma unroll
                for (int eb = 0; eb < 8; ++eb) {
                    if (eb * 4 >= dg) break;     // divergent quad skip (ok)
#pragma unroll
                    for (int u = 0; u < 4; ++u) {
                        const int e = eb * 4 + u;        // compile-time index
                        int p = w[e];
                        float v = (e < dg)
                            ? __uint_as_float((unsigned int)p & 0xFFFF0000u)
                            : 0.f;                        // predicate via value
                        int idx = min(p & 0xFFFF, nm1);   // poison-safe clamp
                        const unsigned short* r0 = xbf + (size_t)idx * D_IN;
                        ushort4 a0 = *(const ushort4*)(r0 + jo);
                        ushort4 b0 = *(const ushort4*)(r0 + 32 + jo);
                        ushort4 c0 = *(const ushort4*)(r0 + 64 + jo);
                        float4 A, B, C;
                        A.x = bfbits(a0.x); A.y = bfbits(a0.y); A.z = bfbits(a0.z); A.w = bfbits(a0.w);
                        B.x = bfbits(b0.x); B.y = bfbits(b0.y); B.z = bfbits(b0.z); B.w = bfbits(b0.w);
                        C.x = bfbits(c0.x); C.y = bfbits(c0.y); C.z = bfbits(c0.z); C.w = bfbits(c0.w);
                        EDGE_FMA(v, A, B, C)
                    }
                }
                // residual: dg > 32 (rare)
                for (int e = 32; e < dg; ++e) {
                    int p0 = __builtin_nontemporal_load(ep + e);
                    float v0 = __uint_as_float((unsigned int)p0 & 0xFFFF0000u);
                    const unsigned short* r0 = xbf + (size_t)(p0 & 0xFFFF) * D_IN;
                    ushort4 a0 = *(const ushort4*)(r0 + jo);
                    ushort4 b0 = *(const ushort4*)(r0 + 32 + jo);
                    ushort4 c0 = *(const ushort4*)(r0 + 64 + jo);
                    float4 A, B, C;
                    A.x = bfbits(a0.x); A.y = bfbits(a0.y); A.z = bfbits(a0.z); A.w = bfbits(a0.w);
                    B.x = bfbits(b0.x); B.y = bfbits(b0.y); B.z = bfbits(b0.z); B.w = bfbits(b0.w);
                    C.x = bfbits(c0.x); C.y = bfbits(c0.y); C.z = bfbits(c0.z); C.w = bfbits(c0.w);
                    EDGE_FMA(v0, A, B, C)
                }
                // eps * self
                {
                    float4 A, B, C;
                    A.x = bfbits(sa.x); A.y = bfbits(sa.y); A.z = bfbits(sa.z); A.w = bfbits(sa.w);
                    B.x = bfbits(sb.x); B.y = bfbits(sb.y); B.z = bfbits(sb.z); B.w = bfbits(sb.w);
                    C.x = bfbits(sc.x); C.y = bfbits(sc.y); C.z = bfbits(sc.z); C.w = bfbits(sc.w);
                    EDGE_FMA(epsv, A, B, C)
                }
            } else {
                // fp32 fallback: same interleaved mapping (float4 at 16B*j
                // per 128B chunk -> 2 segs/row/instr vs 6 before)
                int e = 0;
                for (; e + 2 <= dg; e += 2) {
                    int p0 = __builtin_nontemporal_load(ep + e);
                    int p1 = __builtin_nontemporal_load(ep + e + 1);
                    float v0 = __uint_as_float((unsigned int)p0 & 0xFFFF0000u);
                    float v1 = __uint_as_float((unsigned int)p1 & 0xFFFF0000u);
                    const float* r0 = x + (size_t)(p0 & 0xFFFF) * D_IN;
                    const float* r1 = x + (size_t)(p1 & 0xFFFF) * D_IN;
                    float4 A0 = *(const float4*)(r0 + jo), B0 = *(const float4*)(r0 + 32 + jo), C0 = *(const float4*)(r0 + 64 + jo);
                    float4 A1 = *(const float4*)(r1 + jo), B1 = *(const float4*)(r1 + 32 + jo), C1 = *(const float4*)(r1 + 64 + jo);
                    EDGE_FMA(v0, A0, B0, C0)
                    EDGE_FMA(v1, A1, B1, C1)
                }
                for (; e < dg; ++e) {
                    int p0 = __builtin_nontemporal_load(ep + e);
                    float v0 = __uint_as_float((unsigned int)p0 & 0xFFFF0000u);
                    const float* r0 = x + (size_t)(p0 & 0xFFFF) * D_IN;
                    float4 A0 = *(const float4*)(r0 + jo), B0 = *(const float4*)(r0 + 32 + jo), C0 = *(const float4*)(r0 + 64 + jo);
                    EDGE_FMA(v0, A0, B0, C0)
                }
                const float* rr = x + (size_t)row * D_IN;
                float4 A0 = *(const float4*)(rr + jo), B0 = *(const float4*)(rr + 32 + jo), C0 = *(const float4*)(rr + 64 + jo);
                EDGE_FMA(epsv, A0, B0, C0)
            }
        }
#undef EDGE_FMA
        // Abuf write, interleaved mapping: chunk c (dword base c*16) gets
        // acc[4c..4c+3] at dwords c*16 + 2j + {0,1}. 3x 8B LDS writes
        // (byte addr rl*208 + c*64 + j*8 -> 8B aligned).
        {
            unsigned int* ab = (unsigned int*)&Abuf[rl][0];
            uintx2 w0, w1, w2;
            w0.x = (unsigned int)f2bf(acc[0]) | ((unsigned int)f2bf(acc[1]) << 16);
            w0.y = (unsigned int)f2bf(acc[2]) | ((unsigned int)f2bf(acc[3]) << 16);
            w1.x = (unsigned int)f2bf(acc[4]) | ((unsigned int)f2bf(acc[5]) << 16);
            w1.y = (unsigned int)f2bf(acc[6]) | ((unsigned int)f2bf(acc[7]) << 16);
            w2.x = (unsigned int)f2bf(acc[8]) | ((unsigned int)f2bf(acc[9]) << 16);
            w2.y = (unsigned int)f2bf(acc[10]) | ((unsigned int)f2bf(acc[11]) << 16);
            *(uintx2*)(ab      + (j << 1)) = w0;
            *(uintx2*)(ab + 16 + (j << 1)) = w1;
            *(uintx2*)(ab + 32 + (j << 1)) = w2;
        }
    }
    __syncthreads();

    const int lane = tid & 63;
    const int wid  = tid >> 6;        // wave: cols [wid*64, wid*64+64)
    const int quad = lane >> 4;
    const int nl   = lane & 15;

    // ---- GEMM1 (M=32, N=64/wave, K=96) ------------------------------------
    floatx4 acc1[2][4];
#pragma unroll
    for (int mt = 0; mt < 2; ++mt)
#pragma unroll
        for (int nt = 0; nt < 4; ++nt)
            acc1[mt][nt] = (floatx4){0.f, 0.f, 0.f, 0.f};

#pragma unroll
    for (int kb = 0; kb < 3; ++kb) {
        short8 af0 = *(const short8*)&Abuf[nl     ][kb * 32 + quad * 8];
        short8 af1 = *(const short8*)&Abuf[16 + nl][kb * 32 + quad * 8];
#pragma unroll
        for (int nt = 0; nt < 4; ++nt) {
            const unsigned short* bp =
                W0p + ((size_t)(kb * 256 + wid * 64 + nt * 16 + nl)) * 32 + quad * 8;
            short8 bf = *(const short8*)bp;
            acc1[0][nt] = __builtin_amdgcn_mfma_f32_16x16x32_bf16(af0, bf, acc1[0][nt], 0, 0, 0);
            acc1[1][nt] = __builtin_amdgcn_mfma_f32_16x16x32_bf16(af1, bf, acc1[1][nt], 0, 0, 0);
        }
    }
    __syncthreads();   // Abuf fully consumed by ALL waves before Hbuf overwrite

    // ---- BN + ReLU -> Hbuf (bf16, A-layout for GEMM2) ---------------------
#pragma unroll
    for (int mt = 0; mt < 2; ++mt)
#pragma unroll
        for (int nt = 0; nt < 4; ++nt) {
            int ncol = wid * 64 + nt * 16 + nl;
            float sc = bn_scale[ncol], sh = bn_shift[ncol];
#pragma unroll
            for (int r = 0; r < 4; ++r) {
                float h = fmaxf(0.f, fmaf(acc1[mt][nt][r], sc, sh));
                Hbuf[mt * 16 + quad * 4 + r][ncol] = f2bf(h);
            }
        }
    __syncthreads();

    // ---- GEMM2 (M=32, N=64/wave, K=256) -----------------------------------
    floatx4 acc2[2][4];
#pragma unroll
    for (int mt = 0; mt < 2; ++mt)
#pragma unroll
        for (int nt = 0; nt < 4; ++nt)
            acc2[mt][nt] = (floatx4){0.f, 0.f, 0.f, 0.f};

#pragma unroll
    for (int kb = 0; kb < 8; ++kb) {
        short8 af0 = *(const short8*)&Hbuf[nl     ][kb * 32 + quad * 8];
        short8 af1 = *(const short8*)&Hbuf[16 + nl][kb * 32 + quad * 8];
#pragma unroll
        for (int nt = 0; nt < 4; ++nt) {
            const unsigned short* bp =
                W1p + ((size_t)(kb * 256 + wid * 64 + nt * 16 + nl)) * 32 + quad * 8;
            short8 bf = *(const short8*)bp;
            acc2[0][nt] = __builtin_amdgcn_mfma_f32_16x16x32_bf16(af0, bf, acc2[0][nt], 0, 0, 0);
            acc2[1][nt] = __builtin_amdgcn_mfma_f32_16x16x32_bf16(af1, bf, acc2[1][nt], 0, 0, 0);
        }
    }

    // ---- Store ------------------------------------------------------------
#pragma unroll
    for (int mt = 0; mt < 2; ++mt)
#pragma unroll
        for (int nt = 0; nt < 4; ++nt) {
            int ncol = wid * 64 + nt * 16 + nl;
#pragma unroll
            for (int r = 0; r < 4; ++r) {
                int m = rowbase + mt * 16 + quad * 4 + r;
                if (m < n)
                    __builtin_nontemporal_store(acc2[mt][nt][r],
                                                out + (size_t)m * D_OUT + ncol);
            }
        }
}

extern "C" void kernel_launch(void* const* d_in, const int* in_sizes, int n_in,
                              void* d_out, int out_size, void* d_ws, size_t ws_size,
                              hipStream_t stream) {
    const float* x       = (const float*)d_in[0];
    const int*   src     = (const int*)  d_in[1];
    const int*   dst     = (const int*)  d_in[2];
    const float* vals    = (const float*)d_in[3];
    const float* epsp    = (const float*)d_in[4];
    const float* W0      = (const float*)d_in[5];
    const float* W1      = (const float*)d_in[6];
    const float* gamma   = (const float*)d_in[7];
    const float* beta    = (const float*)d_in[8];
    const float* bn_mean = (const float*)d_in[9];
    const float* bn_var  = (const float*)d_in[10];
    float* out = (float*)d_out;

    const int n = in_sizes[0] / D_IN;
    const int E = in_sizes[1];

    // workspace layout (re-poisoned every call -> rebuild everything)
    int* cursor = (int*)d_ws;                               // N_PAD ints
    int* bucket = cursor + N_PAD;                           // n*CAP ints (12.8 MB)
    unsigned short* W0p = (unsigned short*)(bucket + (size_t)n * CAP);
    unsigned short* W1p = W0p + 3 * 256 * 32;
    unsigned short* xbf = W1p + 8 * 256 * 32;               // n*96 bf16 (9.6 MB), optional

    const size_t base_need = (size_t)(N_PAD + (size_t)n * CAP) * 4
                           + (size_t)(3 + 8) * 256 * 32 * 2;
    const bool use_bf16x = ws_size >= base_need + (size_t)n * D_IN * 2;

    (void)hipMemsetAsync(cursor, 0, (size_t)n * sizeof(int), stream);

    const int nscat = (E + 255) / 256;                      // 1 edge/thread
    const int nxc   = use_bf16x ? ((n * D_IN / 8) + 255) / 256 : 0;  // 8 elems/thread
    const int nwc   = ((3 + 8) * 256 * 32 + 255) / 256;
    prep<<<nscat + nxc + nwc, 256, 0, stream>>>(
        src, dst, vals, x, W0, W1, cursor, bucket, xbf, W0p, W1p, E, n, nscat, nxc);

    const int gblocks = (n + TROWS - 1) / TROWS;
    if (use_bf16x)
        gin_fused<true><<<gblocks, 256, 0, stream>>>(
            x, xbf, cursor, bucket, epsp, W0p, W1p,
            gamma, beta, bn_mean, bn_var, out, n);
    else
        gin_fused<false><<<gblocks, 256, 0, stream>>>(
            x, xbf, cursor, bucket, epsp, W0p, W1p,
            gamma, beta, bn_mean, bn_var, out, n);
}